// Round 2
// 5083.541 us; speedup vs baseline: 1.2953x; 1.2953x over previous
//
#include <hip/hip_runtime.h>

#define BB 64
#define HH 1024
#define SS 512

typedef __attribute__((ext_vector_type(8))) short short8;
typedef __attribute__((ext_vector_type(4))) float f32x4;
typedef unsigned long long u64;

__device__ __forceinline__ unsigned short f2bf(float f) {
  union { float f; unsigned u; } v; v.f = f;
  unsigned r = v.u + 0x7fffu + ((v.u >> 16) & 1u);   // RNE
  return (unsigned short)(r >> 16);
}

// ---- prep: fp32 weights -> bf16; h0 -> bf16 buffer 0; optionally x -> bf16 ----
__global__ void gru_prep(const float* __restrict__ wih, const float* __restrict__ whh,
                         const float* __restrict__ h0, const float* __restrict__ x,
                         unsigned short* __restrict__ wih_bf,
                         unsigned short* __restrict__ whh_bf,
                         unsigned short* __restrict__ hbf,
                         unsigned short* __restrict__ xbf, int do_x) {
  const int NT = gridDim.x * blockDim.x;
  const int tid = blockIdx.x * blockDim.x + threadIdx.x;
  for (int i = tid; i < 3 * HH * HH; i += NT) {
    wih_bf[i] = f2bf(wih[i]);
    whh_bf[i] = f2bf(whh[i]);
  }
  for (int i = tid; i < BB * HH; i += NT) hbf[i] = f2bf(h0[i]);
  if (do_x)
    for (int i = tid; i < BB * SS * HH; i += NT) xbf[i] = f2bf(x[i]);
}

// ---- persistent GRU ----
// 256 WGs x 256 thr, 1 WG/CU. WG = (16 hidden cols c0) x (16-row batch quarter m0).
// K=1024 split across 4 waves; weights register-resident.
// h exchange: per-producer epoch flags (release STORE, no RMW), lane-parallel
// per-wave polling (no thread-0 spin, no pre-h barrier), coalesced 16B
// sc0+sc1 bypassing loads staged through an XOR-swizzled LDS slab.
// Spin is BOUNDED: a protocol bug degrades to wrong-answer+counters, not a hang.
__global__ __launch_bounds__(256, 1) void gru_main(
    const float* __restrict__ x, const unsigned short* __restrict__ xbf, const int use_xbf,
    const float* __restrict__ h0,
    const float* __restrict__ bih, const float* __restrict__ bhh,
    const unsigned short* __restrict__ wih_bf, const unsigned short* __restrict__ whh_bf,
    unsigned short* __restrict__ hbf, int* __restrict__ bar, float* __restrict__ out) {
  __shared__ f32x4 ldsv[2 * 4 * 4 * 64];          // [buf][wave][acc4][lane] = 32 KB
  __shared__ short8 hslab8[4 * 16 * 32];          // per-wave h staging slab   = 32 KB
  __shared__ unsigned short hstage[16 * 16];      // epilogue transpose staging

  const int wg   = blockIdx.x;
  const int idx  = (wg >> 3) + (wg & 7) * 32;     // XCD swizzle (perf heuristic only)
  const int c0   = (idx >> 2) * 16;               // hidden colgroup base
  const int m0   = (idx & 3) * 16;                // batch quarter base
  const int q    = idx & 3;                       // flag group (quarter)
  const int cg   = idx >> 2;                      // this WG's producer-flag slot
  const int wv   = threadIdx.x >> 6;
  const int ln   = threadIdx.x & 63;
  const int l15  = ln & 15;
  const int quad = ln >> 4;
  const int kb   = wv * 256 + quad * 8;           // wave K window + A/B frag offset

  // ---- register-resident weights: B-frag rows n=c0+l15, k = kb + kk*32 + e ----
  const unsigned short* wib = wih_bf + (size_t)(c0 + l15) * HH + kb;
  const unsigned short* whb = whh_bf + (size_t)(c0 + l15) * HH + kb;
  short8 Wi[3][8], Wh[3][8];
#pragma unroll
  for (int g = 0; g < 3; ++g)
#pragma unroll
    for (int kk = 0; kk < 8; ++kk) {
      Wi[g][kk] = *(const short8*)(wib + (size_t)g * HH * HH + kk * 32);
      Wh[g][kk] = *(const short8*)(whb + (size_t)g * HH * HH + kk * 32);
    }

  const int j = c0 + l15;                         // hidden col this lane owns
  const float br   = bih[j] + bhh[j];
  const float bz   = bih[HH + j] + bhh[HH + j];
  const float bi_n = bih[2 * HH + j];
  const float bh_n = bhh[2 * HH + j];

  // fp32 master h (wave 0; C/D layout rows m0+quad*4+i, col j)
  f32x4 hreg;
#pragma unroll
  for (int i = 0; i < 4; ++i) hreg[i] = h0[(m0 + quad * 4 + i) * HH + j];

  const float*          xfp = x   + (size_t)(m0 + l15) * (SS * HH) + kb;
  const unsigned short* xbp = xbf + (size_t)(m0 + l15) * (SS * HH) + kb;

  char* const hsl  = (char*)hslab8 + wv * 8192;   // this wave's 16x256 bf16 slab
  const int   srow = ln >> 5;                     // staging: row parity within pair
  const int   schk = ln & 31;                     // staging: 16B chunk in 512B row
  int* const  fl   = bar + q * 64;                // 64 producer flags for my quarter

#define LOAD_AX(tt)                                                          \
  if (use_xbf) {                                                             \
    const unsigned short* xp = xbp + (size_t)(tt) * HH;                      \
    _Pragma("unroll")                                                        \
    for (int kk = 0; kk < 8; ++kk) ax[kk] = *(const short8*)(xp + kk * 32);  \
  } else {                                                                   \
    const float* xp = xfp + (size_t)(tt) * HH;                               \
    _Pragma("unroll")                                                        \
    for (int kk = 0; kk < 8; ++kk) {                                         \
      float4 xa = *(const float4*)(xp + kk * 32);                            \
      float4 xb = *(const float4*)(xp + kk * 32 + 4);                        \
      short8 v;                                                              \
      v[0] = (short)f2bf(xa.x); v[1] = (short)f2bf(xa.y);                    \
      v[2] = (short)f2bf(xa.z); v[3] = (short)f2bf(xa.w);                    \
      v[4] = (short)f2bf(xb.x); v[5] = (short)f2bf(xb.y);                    \
      v[6] = (short)f2bf(xb.z); v[7] = (short)f2bf(xb.w);                    \
      ax[kk] = v;                                                            \
    }                                                                        \
  }

  short8 ax[8];
  LOAD_AX(0);

#pragma unroll 1
  for (int t = 0; t < SS; ++t) {
    const int buf = (t & 1) * (4 * 4 * 64);

    // ---- h-independent half: x-projection MFMAs (ax prefetched last iter) ----
    f32x4 a0 = {0.f, 0.f, 0.f, 0.f}, a1 = a0, a2 = a0;
#pragma unroll
    for (int kk = 0; kk < 8; ++kk) {
      a0 = __builtin_amdgcn_mfma_f32_16x16x32_bf16(ax[kk], Wi[0][kk], a0, 0, 0, 0);
      a1 = __builtin_amdgcn_mfma_f32_16x16x32_bf16(ax[kk], Wi[1][kk], a1, 0, 0, 0);
      a2 = __builtin_amdgcn_mfma_f32_16x16x32_bf16(ax[kk], Wi[2][kk], a2, 0, 0, 0);
    }

    // ---- wait for h_t: per-wave lane-parallel poll of 64 producer epoch flags.
    // Pure reads (no RMW anywhere); relaxed + control dep orders the bypassing
    // h loads after observation (flag store is release -> data is at L3).
    // BOUNDED: cap converts any protocol bug into wrong-answer, never a hang. ----
    if (t > 0) {
      int spin = 0;
      for (;;) {
        int v = __hip_atomic_load(&fl[ln], __ATOMIC_RELAXED, __HIP_MEMORY_SCOPE_AGENT);
        if (__all(v >= t)) break;
        if (++spin > (1 << 15)) break;            // ~11 ms worst case, never in practice
        __builtin_amdgcn_s_sleep(2);
      }
    }

    // ---- stage h slab: coalesced 16B L1/L2-bypassing loads -> swizzled LDS ----
    const char* hsrc = (const char*)(hbf + (t & 1) * (BB * HH)) +
                       (size_t)m0 * 2048 + wv * 512;
    f32x4 hr[8];
#pragma unroll
    for (int r = 0; r < 8; ++r) {
      const int row = 2 * r + srow;
      const void* p = hsrc + (size_t)row * 2048 + schk * 16;
      asm volatile("global_load_dwordx4 %0, %1, off sc0 sc1"
                   : "=v"(hr[r]) : "v"(p));
    }
    asm volatile("s_waitcnt vmcnt(0)" ::: "memory");
    __builtin_amdgcn_sched_barrier(0);
#pragma unroll
    for (int r = 0; r < 8; ++r) {
      const int row = 2 * r + srow;
      *(f32x4*)(hsl + row * 512 + ((schk * 16) ^ ((row & 7) << 4))) = hr[r];
    }

    // ---- h half: swizzled ds_read_b128 fragments + MFMAs ----
    f32x4 a3 = {0.f, 0.f, 0.f, 0.f}, a4 = a3, a5 = a3;
#pragma unroll
    for (int kk = 0; kk < 8; ++kk) {
      short8 ah = *(const short8*)(hsl + l15 * 512 +
                                   ((quad * 16 + kk * 64) ^ ((l15 & 7) << 4)));
      a3 = __builtin_amdgcn_mfma_f32_16x16x32_bf16(ah, Wh[0][kk], a3, 0, 0, 0);
      a4 = __builtin_amdgcn_mfma_f32_16x16x32_bf16(ah, Wh[1][kk], a4, 0, 0, 0);
      a5 = __builtin_amdgcn_mfma_f32_16x16x32_bf16(ah, Wh[2][kk], a5, 0, 0, 0);
    }
    a0 += a3;   // r gate: x-part + h-part combine
    a1 += a4;   // z gate: combine
                // n gate: a2 (x_n) and a5 (h_n) must stay separate (r scales h_n)

    ldsv[buf + (wv * 4 + 0) * 64 + ln] = a0;
    ldsv[buf + (wv * 4 + 1) * 64 + ln] = a1;
    ldsv[buf + (wv * 4 + 2) * 64 + ln] = a2;
    ldsv[buf + (wv * 4 + 3) * 64 + ln] = a5;
    __syncthreads();

    if (wv != 0) {
      // ---- non-epilogue waves: prefetch next x immediately (hides HBM lat) ----
      if (t + 1 < SS) { LOAD_AX(t + 1); }
    } else {
      // ---- epilogue: wave 0 reduces K-partials, applies gates, publishes h ----
      f32x4 sv[4];
#pragma unroll
      for (int a = 0; a < 4; ++a) {
        sv[a] = ldsv[buf + a * 64 + ln];
#pragma unroll
        for (int w = 1; w < 4; ++w) sv[a] += ldsv[buf + (w * 4 + a) * 64 + ln];
      }
#pragma unroll
      for (int i = 0; i < 4; ++i) {
        float r = 1.f / (1.f + __expf(-(sv[0][i] + br)));
        float z = 1.f / (1.f + __expf(-(sv[1][i] + bz)));
        float pre = sv[2][i] + bi_n + r * (sv[3][i] + bh_n);
        float e2 = __expf(2.f * pre);
        float n = 1.f - 2.f / (e2 + 1.f);       // tanh
        float hnew = (1.f - z) * n + z * hreg[i];
        hreg[i] = hnew;
        hstage[(quad * 4 + i) * 16 + l15] = f2bf(hnew);   // transpose staging
      }
      // pack 4 contiguous bf16 per lane, publish via bypassing store
      const int nxt = ((t + 1) & 1) * (BB * HH);
      u64 pk = *(const u64*)&hstage[(ln >> 2) * 16 + (ln & 3) * 4];
      u64* hdst = (u64*)(hbf + nxt) + (((m0 + (ln >> 2)) * HH + c0) >> 2) + (ln & 3);
      __hip_atomic_store(hdst, pk, __ATOMIC_RELAXED, __HIP_MEMORY_SCOPE_AGENT);
      // release STORE of epoch flag: drains ONLY the h store (x prefetch is
      // deferred past this point for wave 0 -> shortest possible drain)
      if (ln == 0 && t + 1 < SS)
        __hip_atomic_store(&fl[cg], t + 1, __ATOMIC_RELEASE, __HIP_MEMORY_SCOPE_AGENT);
      // x prefetch + out[] stores AFTER the release: off the critical path
      if (t + 1 < SS) { LOAD_AX(t + 1); }
#pragma unroll
      for (int i = 0; i < 4; ++i) {
        const int b = m0 + quad * 4 + i;
        __builtin_nontemporal_store(hreg[i],
            &out[(size_t)b * (SS * HH) + (size_t)t * HH + j]);
        if (t == SS - 1)
          __builtin_nontemporal_store(hreg[i],
              &out[(size_t)BB * SS * HH + b * HH + j]);
      }
    }
    // next iteration uses the other LDS partial buffer — no tail sync needed
  }
#undef LOAD_AX
}

extern "C" void kernel_launch(void* const* d_in, const int* in_sizes, int n_in,
                              void* d_out, int out_size, void* d_ws, size_t ws_size,
                              hipStream_t stream) {
  const float* x   = (const float*)d_in[0];
  const float* h0  = (const float*)d_in[1];
  const float* wih = (const float*)d_in[2];
  const float* whh = (const float*)d_in[3];
  const float* bih = (const float*)d_in[4];
  const float* bhh = (const float*)d_in[5];
  float* out = (float*)d_out;

  char* ws = (char*)d_ws;
  const size_t off_whh = 6291456;            // 3*1024*1024*2
  const size_t off_h   = 12582912;
  const size_t off_bar = 12845056;           // after 2 h buffers (262144 B)
  const size_t off_x   = 12853248;           // after flag array (8192 B)
  const size_t need_x  = off_x + (size_t)BB * SS * HH * 2;   // ~80 MB

  unsigned short* wih_bf = (unsigned short*)ws;
  unsigned short* whh_bf = (unsigned short*)(ws + off_whh);
  unsigned short* hbf    = (unsigned short*)(ws + off_h);
  int*            bar    = (int*)(ws + off_bar);
  unsigned short* xbf    = (unsigned short*)(ws + off_x);
  const int use_xbf = (ws_size >= need_x) ? 1 : 0;

  hipMemsetAsync(bar, 0, 8192, stream);      // ws is poisoned; epoch flags start at 0
  hipLaunchKernelGGL(gru_prep, dim3(2048), dim3(256), 0, stream,
                     wih, whh, h0, x, wih_bf, whh_bf, hbf, xbf, use_xbf);
  hipLaunchKernelGGL(gru_main, dim3(256), dim3(256), 0, stream,
                     x, xbf, use_xbf, h0, bih, bhh, wih_bf, whh_bf, hbf, bar, out);
}

// Round 3
// 3080.886 us; speedup vs baseline: 2.1373x; 1.6500x over previous
//
#include <hip/hip_runtime.h>

#define BB 64
#define HH 1024
#define SS 512

typedef __attribute__((ext_vector_type(8))) short short8;
typedef __attribute__((ext_vector_type(4))) float f32x4;
typedef __attribute__((ext_vector_type(4))) unsigned u32x4;
typedef unsigned long long u64;

__device__ __forceinline__ unsigned short f2bf(float f) {
  union { float f; unsigned u; } v; v.f = f;
  unsigned r = v.u + 0x7fffu + ((v.u >> 16) & 1u);   // RNE
  return (unsigned short)(r >> 16);
}

// ---- prep: fp32 weights -> bf16; h0 -> tagged buffer 0 (tag=0); poison buffer 1;
//      optionally x -> bf16 ----
__global__ void gru_prep(const float* __restrict__ wih, const float* __restrict__ whh,
                         const float* __restrict__ h0, const float* __restrict__ x,
                         unsigned short* __restrict__ wih_bf,
                         unsigned short* __restrict__ whh_bf,
                         unsigned* __restrict__ htag,
                         unsigned short* __restrict__ xbf, int do_x) {
  const int NT = gridDim.x * blockDim.x;
  const int tid = blockIdx.x * blockDim.x + threadIdx.x;
  for (int i = tid; i < 3 * HH * HH; i += NT) {
    wih_bf[i] = f2bf(wih[i]);
    whh_bf[i] = f2bf(whh[i]);
  }
  for (int i = tid; i < BB * HH; i += NT) {
    htag[i]           = (unsigned)f2bf(h0[i]);   // tag 0 in high16
    htag[BB * HH + i] = 0xFFFF0000u;             // buffer1: invalid tag (ws is poisoned)
  }
  if (do_x)
    for (int i = tid; i < BB * SS * HH; i += NT) xbf[i] = f2bf(x[i]);
}

// ---- persistent GRU ----
// 256 WGs x 256 thr, 1 WG/CU. WG = (16 hidden cols c0) x (16-row batch quarter m0).
// K=1024 split across 4 waves; weights register-resident.
// h exchange is ONE fabric transit: h published as tagged u32 (tag=t in high16,
// bf16 value in low16). A 4B store is atomic -> validity is per-word; detect and
// fetch are the SAME sc0+sc1 load. No flags, no release drain, no poll loop, no
// LDS staging. Each wave validates only its own 16-producer K-window. Retry is
// BOUNDED (protocol bug -> wrong answer + counters, never a hang).
// Epilogue is parallelized across all 4 waves (scalar per-lane gates).
__global__ __launch_bounds__(256, 1) void gru_main(
    const float* __restrict__ x, const unsigned short* __restrict__ xbf, const int use_xbf,
    const float* __restrict__ h0,
    const float* __restrict__ bih, const float* __restrict__ bhh,
    const unsigned short* __restrict__ wih_bf, const unsigned short* __restrict__ whh_bf,
    unsigned* __restrict__ htag, float* __restrict__ out) {
  __shared__ f32x4 ldsv[2 * 4 * 4 * 64];          // [buf][wave][gate][lane] = 32 KB

  const int wg   = blockIdx.x;
  const int idx  = (wg >> 3) + (wg & 7) * 32;     // XCD swizzle (perf heuristic only)
  const int c0   = (idx >> 2) * 16;               // hidden colgroup base
  const int m0   = (idx & 3) * 16;                // batch quarter base
  const int wv   = threadIdx.x >> 6;
  const int ln   = threadIdx.x & 63;
  const int l15  = ln & 15;                       // A-frag batch row / epilogue col
  const int quad = ln >> 4;                       // A-frag k-subblock / epilogue rowoff
  const int kb   = wv * 256 + quad * 8;           // wave K window + A/B frag offset

  // ---- register-resident weights: B-frag rows n=c0+l15, k = kb + kk*32 + e ----
  const unsigned short* wib = wih_bf + (size_t)(c0 + l15) * HH + kb;
  const unsigned short* whb = whh_bf + (size_t)(c0 + l15) * HH + kb;
  short8 Wi[3][8], Wh[3][8];
#pragma unroll
  for (int g = 0; g < 3; ++g)
#pragma unroll
    for (int kk = 0; kk < 8; ++kk) {
      Wi[g][kk] = *(const short8*)(wib + (size_t)g * HH * HH + kk * 32);
      Wh[g][kk] = *(const short8*)(whb + (size_t)g * HH * HH + kk * 32);
    }

  const int j = c0 + l15;                         // hidden col this lane owns
  const float br   = bih[j] + bhh[j];
  const float bz   = bih[HH + j] + bhh[HH + j];
  const float bi_n = bih[2 * HH + j];
  const float bh_n = bhh[2 * HH + j];

  // fp32 master h: this lane owns (row b = m0 + wv*4 + quad, col j)
  const int brow = m0 + wv * 4 + quad;
  float hreg = h0[brow * HH + j];

  const float*          xfp = x   + (size_t)(m0 + l15) * (SS * HH) + kb;
  const unsigned short* xbp = xbf + (size_t)(m0 + l15) * (SS * HH) + kb;
  const int hw_off = (m0 + l15) * HH + kb;        // word offset of this lane's h window

#define LOAD_AX(tt)                                                          \
  if (use_xbf) {                                                             \
    const unsigned short* xp = xbp + (size_t)(tt) * HH;                      \
    _Pragma("unroll")                                                        \
    for (int kk = 0; kk < 8; ++kk) ax[kk] = *(const short8*)(xp + kk * 32);  \
  } else {                                                                   \
    const float* xp = xfp + (size_t)(tt) * HH;                               \
    _Pragma("unroll")                                                        \
    for (int kk = 0; kk < 8; ++kk) {                                         \
      float4 xa = *(const float4*)(xp + kk * 32);                            \
      float4 xb = *(const float4*)(xp + kk * 32 + 4);                        \
      short8 v;                                                              \
      v[0] = (short)f2bf(xa.x); v[1] = (short)f2bf(xa.y);                    \
      v[2] = (short)f2bf(xa.z); v[3] = (short)f2bf(xa.w);                    \
      v[4] = (short)f2bf(xb.x); v[5] = (short)f2bf(xb.y);                    \
      v[6] = (short)f2bf(xb.z); v[7] = (short)f2bf(xb.w);                    \
      ax[kk] = v;                                                            \
    }                                                                        \
  }

// 16 tagged-h 16B loads: kk*128 and kk*128+16 byte offsets, L1/L2-bypassing
#define HLOAD(i, off)                                                        \
  asm volatile("global_load_dwordx4 %0, %1, off offset:" #off " sc0 sc1"     \
               : "=v"(hr[i]) : "v"(hb))
#define ISSUE_H()                                                            \
  do {                                                                       \
    HLOAD(0, 0);    HLOAD(1, 16);   HLOAD(2, 128);  HLOAD(3, 144);           \
    HLOAD(4, 256);  HLOAD(5, 272);  HLOAD(6, 384);  HLOAD(7, 400);           \
    HLOAD(8, 512);  HLOAD(9, 528);  HLOAD(10, 640); HLOAD(11, 656);          \
    HLOAD(12, 768); HLOAD(13, 784); HLOAD(14, 896); HLOAD(15, 912);          \
  } while (0)

  short8 ax[8];
  LOAD_AX(0);

#pragma unroll 1
  for (int t = 0; t < SS; ++t) {
    const int buf = (t & 1) * (4 * 4 * 64);
    const unsigned tagv = (unsigned)t << 16;
    const unsigned* hb = htag + (t & 1) * (BB * HH) + hw_off;

    // ---- 0) issue round-0 tagged-h loads: they fly during the x-MFMAs ----
    u32x4 hr[16];
    ISSUE_H();

    // ---- 1) h-independent half: x-projection MFMAs (ax prefetched) ----
    f32x4 a0 = {0.f, 0.f, 0.f, 0.f}, a1 = a0, a2 = a0;
#pragma unroll
    for (int kk = 0; kk < 8; ++kk) {
      a0 = __builtin_amdgcn_mfma_f32_16x16x32_bf16(ax[kk], Wi[0][kk], a0, 0, 0, 0);
      a1 = __builtin_amdgcn_mfma_f32_16x16x32_bf16(ax[kk], Wi[1][kk], a1, 0, 0, 0);
      a2 = __builtin_amdgcn_mfma_f32_16x16x32_bf16(ax[kk], Wi[2][kk], a2, 0, 0, 0);
    }

    // ---- 2) retry until this wave's 16-producer K-window is fully tag==t ----
#pragma unroll 1
    for (int round = 0;; ++round) {
      asm volatile("s_waitcnt vmcnt(0)" ::: "memory");
      __builtin_amdgcn_sched_barrier(0);            // rule-18: pin checks after wait
      unsigned bad = 0;
#pragma unroll
      for (int i = 0; i < 16; ++i)
        bad |= (hr[i][0] ^ tagv) | (hr[i][1] ^ tagv) |
               (hr[i][2] ^ tagv) | (hr[i][3] ^ tagv);
      const int ok = ((bad & 0xFFFF0000u) == 0);
      if (__all(ok) || round >= 2048) break;        // bounded: no hang possible
      ISSUE_H();
    }

    // ---- 3) prefetch next x NOW: HBM latency hides under hMFMA+epilogue ----
    if (t + 1 < SS) { LOAD_AX(t + 1); }

    // ---- 4) h half: in-register unpack (v_perm) + MFMAs ----
    f32x4 a3 = {0.f, 0.f, 0.f, 0.f}, a4 = a3, a5 = a3;
#pragma unroll
    for (int kk = 0; kk < 8; ++kk) {
      unsigned p0 = __builtin_amdgcn_perm(hr[2 * kk][1],     hr[2 * kk][0],     0x05040100u);
      unsigned p1 = __builtin_amdgcn_perm(hr[2 * kk][3],     hr[2 * kk][2],     0x05040100u);
      unsigned p2 = __builtin_amdgcn_perm(hr[2 * kk + 1][1], hr[2 * kk + 1][0], 0x05040100u);
      unsigned p3 = __builtin_amdgcn_perm(hr[2 * kk + 1][3], hr[2 * kk + 1][2], 0x05040100u);
      union { unsigned u[4]; short8 s; } uu = {{p0, p1, p2, p3}};
      a3 = __builtin_amdgcn_mfma_f32_16x16x32_bf16(uu.s, Wh[0][kk], a3, 0, 0, 0);
      a4 = __builtin_amdgcn_mfma_f32_16x16x32_bf16(uu.s, Wh[1][kk], a4, 0, 0, 0);
      a5 = __builtin_amdgcn_mfma_f32_16x16x32_bf16(uu.s, Wh[2][kk], a5, 0, 0, 0);
    }
    a0 += a3;   // r gate: x-part + h-part combine
    a1 += a4;   // z gate: combine
                // n gate: a2 (x_n) and a5 (h_n) stay separate (r scales h_n)

    ldsv[buf + (wv * 4 + 0) * 64 + ln] = a0;
    ldsv[buf + (wv * 4 + 1) * 64 + ln] = a1;
    ldsv[buf + (wv * 4 + 2) * 64 + ln] = a2;
    ldsv[buf + (wv * 4 + 3) * 64 + ln] = a5;
    __syncthreads();

    // ---- 5) epilogue on ALL 4 waves: wave wv owns rows wv*4..wv*4+3.
    // Lane (col=l15, rowoff=quad) reduces K-partials with 16 2-way-free
    // ds_read_b32, applies gates, publishes ONE tagged u32 + ONE out float ----
    {
      const float* lf = (const float*)(ldsv + buf);
      float s0 = 0.f, s1 = 0.f, s2 = 0.f, s3 = 0.f;
#pragma unroll
      for (int sw = 0; sw < 4; ++sw) {
        const int base = (sw * 4 * 64 + wv * 16 + l15) * 4 + quad;
        s0 += lf[base];       s1 += lf[base + 256];
        s2 += lf[base + 512]; s3 += lf[base + 768];
      }
      float r = 1.f / (1.f + __expf(-(s0 + br)));
      float z = 1.f / (1.f + __expf(-(s1 + bz)));
      float pre = s2 + bi_n + r * (s3 + bh_n);
      float e2 = __expf(2.f * pre);
      float n = 1.f - 2.f / (e2 + 1.f);           // tanh
      float hnew = (1.f - z) * n + z * hreg;
      hreg = hnew;
      if (t + 1 < SS) {
        unsigned pk = (unsigned)f2bf(hnew) | ((unsigned)(t + 1) << 16);
        __hip_atomic_store(htag + ((t + 1) & 1) * (BB * HH) + brow * HH + j, pk,
                           __ATOMIC_RELAXED, __HIP_MEMORY_SCOPE_AGENT);
      }
      __builtin_nontemporal_store(hnew,
          &out[(size_t)brow * (SS * HH) + (size_t)t * HH + j]);
      if (t == SS - 1)
        __builtin_nontemporal_store(hnew, &out[(size_t)BB * SS * HH + brow * HH + j]);
    }
    // next iteration uses the other LDS partial buffer — no tail sync needed
  }
#undef LOAD_AX
#undef HLOAD
#undef ISSUE_H
}

extern "C" void kernel_launch(void* const* d_in, const int* in_sizes, int n_in,
                              void* d_out, int out_size, void* d_ws, size_t ws_size,
                              hipStream_t stream) {
  const float* x   = (const float*)d_in[0];
  const float* h0  = (const float*)d_in[1];
  const float* wih = (const float*)d_in[2];
  const float* whh = (const float*)d_in[3];
  const float* bih = (const float*)d_in[4];
  const float* bhh = (const float*)d_in[5];
  float* out = (float*)d_out;

  char* ws = (char*)d_ws;
  const size_t off_whh = 6291456;            // 3*1024*1024*2
  const size_t off_h   = 12582912;           // tagged h: 2 x 64x1024 u32 = 512 KB
  const size_t off_x   = 13107200;           // after tagged-h buffers
  const size_t need_x  = off_x + (size_t)BB * SS * HH * 2;   // ~80 MB

  unsigned short* wih_bf = (unsigned short*)ws;
  unsigned short* whh_bf = (unsigned short*)(ws + off_whh);
  unsigned*       htag   = (unsigned*)(ws + off_h);
  unsigned short* xbf    = (unsigned short*)(ws + off_x);
  const int use_xbf = (ws_size >= need_x) ? 1 : 0;

  hipLaunchKernelGGL(gru_prep, dim3(2048), dim3(256), 0, stream,
                     wih, whh, h0, x, wih_bf, whh_bf, htag, xbf, use_xbf);
  hipLaunchKernelGGL(gru_main, dim3(256), dim3(256), 0, stream,
                     x, xbf, use_xbf, h0, bih, bhh, wih_bf, whh_bf, htag, out);
}